// Round 10
// baseline (784.198 us; speedup 1.0000x reference)
//
#include <hip/hip_runtime.h>
#include <hip/hip_cooperative_groups.h>

namespace cg = cooperative_groups;

typedef __attribute__((ext_vector_type(8))) short short8;
typedef __attribute__((ext_vector_type(4))) float f32x4;

#define LDS_BYTES 33280   // convw transpose buffer 128*65*4 B (largest phase)

// ---- bf16 helpers (RNE) ----
__device__ __forceinline__ unsigned short f2bf(float f) {
    union { float f; unsigned u; } v; v.f = f;
    unsigned r = v.u + 0x7FFFu + ((v.u >> 16) & 1u);
    return (unsigned short)(r >> 16);
}
__device__ __forceinline__ float bf2f(unsigned short h) {
    union { unsigned u; float f; } v; v.u = ((unsigned)h) << 16;
    return v.f;
}

// ============================================================================
// Single fused cooperative kernel.
//  Phase 1: W_lvl f32 -> Wt bf16 hi/lo, layout [kf][d][kin2], kin2=h*128+s*64+c
//  Phase 2: level-0 input projection -> Va [b][256][64] bf16
//  Phase 3: 8 butterfly levels, grid.sync between. Per tile (p, x):
//           stage A (64 rows x 128 bf16 = 16 KB) in LDS, XOR-16B swizzled;
//           weights in regs (child-serialized bw[8] = 32 VGPR);
//           4 waves own 16-col slices; mfma 16x16x32; bias+relu+bf16 store.
//  Phase 4: output projection against Fea -> out f32.
// ============================================================================
__global__ __launch_bounds__(256, 4) void k_fused(
    const float* __restrict__ in_data, const float* __restrict__ W_in,
    const float* __restrict__ b_in, const float* __restrict__ W_lvl,
    const float* __restrict__ b_lvl, const float* __restrict__ Fea,
    float* __restrict__ out, unsigned short* __restrict__ Wt,
    unsigned short* __restrict__ Va, unsigned short* __restrict__ Vb)
{
    extern __shared__ char lds[];
    const int tid = threadIdx.x;
    cg::grid_group grid = cg::this_grid();

    // ---------------- Phase 1: weight convert (510 blocks of work) ----------
    {
        float* buf = (float*)lds;                       // [128][65] padded
        for (int kf = blockIdx.x; kf < 510; kf += gridDim.x) {
            __syncthreads();                            // cross-iteration reuse
            const float* src = W_lvl + (size_t)kf * 8192;
            for (int m = 0; m < 32; ++m) {
                int idx = m * 256 + tid;                // flat [kin][d]
                int kin = idx >> 6, d = idx & 63;
                buf[kin * 65 + d] = src[idx];
            }
            __syncthreads();
            unsigned short* dst = Wt + (size_t)kf * 16384;
            for (int m = 0; m < 64; ++m) {
                int o = m * 256 + tid;                  // flat [d][kin2]
                int d = o >> 8, kin2 = o & 255, kin = kin2 & 127;
                float val = buf[kin * 65 + d];
                unsigned short hi = f2bf(val);
                dst[o] = (kin2 >> 7) ? f2bf(val - bf2f(hi)) : hi;
            }
        }
    }
    __syncthreads();

    // ---------------- Phase 2: level-0 projection (8192 row-tiles) ----------
    {
        float* wl = (float*)lds;                        // 16*64
        float* bl = wl + 1024;                          // 64
        float* xl = bl + 64;                            // 256
        for (int m = 0; m < 4; ++m) wl[m * 256 + tid] = W_in[m * 256 + tid];
        if (tid < 64) bl[tid] = b_in[tid];
        for (int rt = blockIdx.x; rt < 8192; rt += gridDim.x) {
            const int row0 = rt * 16;
            __syncthreads();                            // xl reuse + wl visibility
            xl[tid] = in_data[(size_t)row0 * 16 + tid];
            __syncthreads();
            const int r = tid >> 4, c0 = (tid & 15) * 4;
            float a0 = bl[c0], a1 = bl[c0+1], a2 = bl[c0+2], a3 = bl[c0+3];
#pragma unroll
            for (int f = 0; f < 16; ++f) {
                float xv = xl[r * 16 + f];
                const float* wr = &wl[f * 64 + c0];
                a0 += xv*wr[0]; a1 += xv*wr[1]; a2 += xv*wr[2]; a3 += xv*wr[3];
            }
            size_t ob = (size_t)(row0 + r) * 64 + c0;
            Va[ob]   = f2bf(fmaxf(a0, 0.f));
            Va[ob+1] = f2bf(fmaxf(a1, 0.f));
            Va[ob+2] = f2bf(fmaxf(a2, 0.f));
            Va[ob+3] = f2bf(fmaxf(a3, 0.f));
        }
    }
    grid.sync();

    // ---------------- Phase 3: butterfly levels ----------------
    const int w  = tid >> 6;                            // col-slice 0..3
    const int l  = tid & 63;
    const int q  = l >> 4;                              // 0..3
    const int ln = l & 15;
    for (int lvl = 1; lvl <= 8; ++lvl) {
        const int T = 1 << (8 - lvl), lgT = 8 - lvl, off = (1 << lvl) - 2;
        const unsigned short* __restrict__ Vcur = (lvl & 1) ? Va : Vb;
        unsigned short* __restrict__ Vnxt = (lvl & 1) ? Vb : Va;
        for (int flat = blockIdx.x; flat < 1024; flat += gridDim.x) {
            const int p = flat >> (11 - lvl);
            const int x = flat & ((1 << (11 - lvl)) - 1);
            __syncthreads();                            // cross-tile LDS reuse
            // stage A: rows x*64..x*64+64 of parent p, 16B-chunk XOR swizzle
            for (int j = 0; j < 4; ++j) {
                int c = tid + j * 256;                  // chunk 0..1023
                int row = c >> 4, sub = c & 15;
                int rg = x * 64 + row;
                int b = rg >> lgT, t = rg & (T - 1);
                const unsigned short* g = Vcur + ((size_t)b << 14) +
                    ((size_t)p << (lgT + 7)) + (size_t)t * 128 + sub * 8;
                short8 v = *(const short8*)g;
                *(short8*)(lds + row * 256 + ((sub * 16) ^ ((row & 7) << 4))) = v;
            }
            __syncthreads();
#pragma unroll
            for (int s = 0; s < 2; ++s) {               // children serialized
                const int kf = off + 2 * p + s;
                short8 bw[8];
                const unsigned short* wbase =
                    Wt + (size_t)kf * 16384 + (size_t)(w * 16 + ln) * 256 + q * 8;
#pragma unroll
                for (int kk = 0; kk < 8; ++kk)
                    bw[kk] = *(const short8*)(wbase + kk * 32);
                const float bias = b_lvl[kf * 64 + w * 16 + ln];
#pragma unroll
                for (int m = 0; m < 4; ++m) {
                    short8 a[4];
#pragma unroll
                    for (int kk = 0; kk < 4; ++kk) {
                        int row = m * 16 + ln;
                        a[kk] = *(const short8*)(lds + row * 256 +
                                 ((q * 16 + kk * 64) ^ ((row & 7) << 4)));
                    }
                    f32x4 acc = {0.f, 0.f, 0.f, 0.f};
#pragma unroll
                    for (int kk = 0; kk < 8; ++kk)
                        acc = __builtin_amdgcn_mfma_f32_16x16x32_bf16(
                            a[kk & 3], bw[kk], acc, 0, 0, 0);
#pragma unroll
                    for (int j = 0; j < 4; ++j) {       // C/D: row=q*4+j, col=ln
                        int rg = x * 64 + m * 16 + q * 4 + j;
                        int bb = rg >> lgT, tt = rg & (T - 1);
                        Vnxt[((size_t)bb << 14) +
                             (size_t)(2 * p + s) * ((size_t)T << 6) +
                             (size_t)tt * 64 + w * 16 + ln] =
                            f2bf(fmaxf(acc[j] + bias, 0.f));
                    }
                }
            }
        }
        grid.sync();
    }

    // ---------------- Phase 4: output projection (8192 (k,b0) tiles) --------
    {
        float* fl = (float*)lds;                        // [64][16]
        unsigned short* vl = (unsigned short*)(lds + 4096); // [16][64]
        for (int it = blockIdx.x; it < 8192; it += gridDim.x) {
            const int k = it & 255, b0 = (it >> 8) * 16;
            __syncthreads();
            for (int m = 0; m < 4; ++m)
                fl[m * 256 + tid] = Fea[(size_t)k * 1024 + m * 256 + tid];
            {
                int idx = tid * 4;
                int bl2 = idx >> 6, c = idx & 63;
                const unsigned short* src = Va + ((size_t)(b0 + bl2) << 14) + k * 64 + c;
                *(uint2*)&vl[idx] = *(const uint2*)src;
            }
            __syncthreads();
            const int bl2 = tid >> 4, f = tid & 15;
            float acc = 0.f;
#pragma unroll
            for (int c = 0; c < 64; ++c)
                acc += bf2f(vl[bl2 * 64 + c]) * fl[c * 16 + f];
            out[(size_t)(b0 + bl2) * 4096 + (size_t)k * 16 + f] = acc;
        }
    }
}

// ============================================================================
extern "C" void kernel_launch(void* const* d_in, const int* in_sizes, int n_in,
                              void* d_out, int out_size, void* d_ws, size_t ws_size,
                              hipStream_t stream) {
    const float* in_data = (const float*)d_in[0];
    const float* W_in    = (const float*)d_in[1];
    const float* b_in    = (const float*)d_in[2];
    const float* W_lvl   = (const float*)d_in[3];
    const float* b_lvl   = (const float*)d_in[4];
    const float* Fea     = (const float*)d_in[5];
    float* out = (float*)d_out;

    // workspace: Wt bf16 (16,711,680 B) | Va (16,777,216 B) | Vb (16,777,216 B)
    unsigned short* Wt = (unsigned short*)d_ws;
    unsigned short* Va = (unsigned short*)((char*)d_ws + 16711680);
    unsigned short* Vb = (unsigned short*)((char*)d_ws + 16711680 + 16777216);

    int maxPerCU = 0;
    hipOccupancyMaxActiveBlocksPerMultiprocessor(&maxPerCU, k_fused, 256,
                                                 (size_t)LDS_BYTES);
    if (maxPerCU < 1) maxPerCU = 1;
    int nb = maxPerCU * 256;          // 256 CUs on MI355X
    if (nb > 1024) nb = 1024;

    void* args[] = {(void*)&in_data, (void*)&W_in, (void*)&b_in, (void*)&W_lvl,
                    (void*)&b_lvl, (void*)&Fea, (void*)&out, (void*)&Wt,
                    (void*)&Va, (void*)&Vb};
    hipLaunchCooperativeKernel(k_fused, dim3(nb), dim3(256), args,
                               (unsigned int)LDS_BYTES, stream);
}